// Round 3
// baseline (190.988 us; speedup 1.0000x reference)
//
#include <hip/hip_runtime.h>
#include <math.h>

#define Bc 2
#define Vc 5
#define Cc 32
#define Dc 32
#define Hc 128
#define Wc 160
#define HWc (Hc*Wc)
#define NSLOT 48

// ---- workspace layout (in floats; _I suffixes are int-indexed via (int*)ws) ----
#define WS_RT     0                       // 8 * 12 floats (rot 9 + trans 3)
#define WS_KW     96                      // 27 collapsed conv taps
#define FLAG_I    128                     // int[2]: [128] translation-ok, [129] dvals-uniform
#define NS_I      136                     // int[8]: slots used per (b,v)
#define SHIFT_I   144                     // 8 * NSLOT * 2 ints (dx,dy)
#define WS_TAPID  912                     // 8 * 32 records * 9 (4 int ids, wx, wy, pad3)
#define WS_M      3584                    // fast: 8 * NSLOT * HW maps | fallback: FEATT overlay | later: PRE overlay
#define WS_FEATT  WS_M
#define WS_PRE    WS_M
#define WS_SIM    (WS_M + 8*NSLOT*HWc)    // B * D * HW, d-major
// end = WS_SIM + Bc*Dc*HWc = 9,178,624 floats (~36.7 MB)

// ---- output layout (in floats) ----
#define OUT_DEPTH 0
#define OUT_CONF  (Bc*HWc)
#define OUT_PROB  (2*Bc*HWc)
#define OUT_VW    (2*Bc*HWc + Bc*Dc*HWc)

// k0: matrices, translation check, shift/tap tables, collapsed conv kernel
__global__ void prep_kernel(const float* __restrict__ pm, const float* __restrict__ reg_w,
                            const float* __restrict__ dvals, float* __restrict__ ws) {
    __shared__ int okS[8];
    int* wsi = (int*)ws;
    int t = threadIdx.x;
    if (t < Bc * (Vc - 1)) {
        int b = t / (Vc - 1);
        int v = t % (Vc - 1) + 1;
        float Pv[16], P0[16];
        for (int which = 0; which < 2; ++which) {
            int vv = which ? 0 : v;
            const float* E = pm + ((b * Vc + vv) * 2 + 0) * 16;
            const float* K = pm + ((b * Vc + vv) * 2 + 1) * 16;
            float* P = which ? P0 : Pv;
            for (int i = 0; i < 3; ++i)
                for (int j = 0; j < 4; ++j) {
                    float s = 0.f;
                    for (int k = 0; k < 3; ++k) s += K[i*4+k] * E[k*4+j];
                    P[i*4+j] = s;
                }
            for (int j = 0; j < 4; ++j) P[12+j] = E[12+j];
        }
        float A[16], I[16];
        for (int i = 0; i < 16; ++i) { A[i] = P0[i]; I[i] = (i % 5 == 0) ? 1.f : 0.f; }
        for (int col = 0; col < 4; ++col) {
            int piv = col; float best = fabsf(A[col*4+col]);
            for (int r = col+1; r < 4; ++r) { float av = fabsf(A[r*4+col]); if (av > best) { best = av; piv = r; } }
            if (piv != col)
                for (int j = 0; j < 4; ++j) {
                    float tmp = A[col*4+j]; A[col*4+j] = A[piv*4+j]; A[piv*4+j] = tmp;
                    tmp = I[col*4+j]; I[col*4+j] = I[piv*4+j]; I[piv*4+j] = tmp;
                }
            float inv = 1.f / A[col*4+col];
            for (int j = 0; j < 4; ++j) { A[col*4+j] *= inv; I[col*4+j] *= inv; }
            for (int r = 0; r < 4; ++r) if (r != col) {
                float f = A[r*4+col];
                for (int j = 0; j < 4; ++j) { A[r*4+j] -= f * A[col*4+j]; I[r*4+j] -= f * I[col*4+j]; }
            }
        }
        float M[16];
        for (int i = 0; i < 4; ++i)
            for (int j = 0; j < 4; ++j) {
                float s = 0.f;
                for (int k = 0; k < 4; ++k) s += Pv[i*4+k] * I[k*4+j];
                M[i*4+j] = s;
            }
        float* rt = ws + WS_RT + t * 12;
        for (int i = 0; i < 3; ++i)
            for (int j = 0; j < 3; ++j) rt[i*3+j] = M[i*4+j];
        rt[9] = M[3]; rt[10] = M[7]; rt[11] = M[11];

        // translation-form check
        float t0 = M[3], t1 = M[7], t2 = M[11];
        bool ok = fabsf(M[0]-1.f) < 3e-5f && fabsf(M[1]) < 3e-5f && fabsf(M[2]) < 3e-5f &&
                  fabsf(M[4]) < 3e-5f && fabsf(M[5]-1.f) < 3e-5f && fabsf(M[6]) < 3e-5f &&
                  fabsf(M[8]) < 1e-6f && fabsf(M[9]) < 1e-6f && fabsf(M[10]-1.f) < 1e-6f &&
                  fabsf(t2) < 1e-6f;
        if (ok) {
            int n = 0;
            int pid0 = 0, pid1 = 0, pid2 = 0, pid3 = 0, pix = 0, piy = 0;
            for (int d = 0; d < Dc; ++d) {
                float dv = dvals[(size_t)(b * Dc + d) * HWc];
                float sx = t0 / dv, sy = t1 / dv;
                float fx0 = floorf(sx), fy0 = floorf(sy);
                int ix = (int)fx0, iy = (int)fy0;
                float wx = sx - fx0, wy = sy - fy0;
                int dxi = ix - pix, dyi = iy - piy;
                bool reuse = (d > 0) && dxi >= -1 && dxi <= 1 && dyi >= -1 && dyi <= 1;
                int id0, id1, id2, id3;
                // tap (tx,ty): coords (ix+tx, iy+ty); prev-tap (tx+dxi, ty+dyi)
                #define GETPREV(tx2, ty2) ((ty2)==0 ? ((tx2)==0 ? pid0 : pid1) : ((tx2)==0 ? pid2 : pid3))
                #define DOTAP(idv, tx, ty) { \
                    int tx2 = (tx) + dxi, ty2 = (ty) + dyi; \
                    if (reuse && tx2 >= 0 && tx2 <= 1 && ty2 >= 0 && ty2 <= 1) idv = GETPREV(tx2, ty2); \
                    else { if (n < NSLOT) { wsi[SHIFT_I + (t*NSLOT + n)*2] = ix + (tx); \
                                            wsi[SHIFT_I + (t*NSLOT + n)*2 + 1] = iy + (ty); } \
                           idv = n++; } }
                DOTAP(id0, 0, 0)
                DOTAP(id1, 1, 0)
                DOTAP(id2, 0, 1)
                DOTAP(id3, 1, 1)
                #undef DOTAP
                #undef GETPREV
                int base = WS_TAPID + (t * Dc + d) * 9;
                wsi[base+0] = id0; wsi[base+1] = id1; wsi[base+2] = id2; wsi[base+3] = id3;
                ws[base+4] = wx; ws[base+5] = wy;
                pid0 = id0; pid1 = id1; pid2 = id2; pid3 = id3; pix = ix; piy = iy;
            }
            if (n > NSLOT) ok = false;
            wsi[NS_I + t] = (n > NSLOT) ? 0 : n;
        } else {
            wsi[NS_I + t] = 0;
        }
        okS[t] = ok ? 1 : 0;
    }
    if (t >= 32 && t < 32 + 27) {
        int k = t - 32;
        float s = 0.f;
        for (int c = 0; c < Cc; ++c) s += reg_w[c * 27 + k];
        ws[WS_KW + k] = s;
    }
    __syncthreads();
    if (t == 0) {
        int f = 1;
        for (int i = 0; i < 8; ++i) f &= okS[i];
        wsi[FLAG_I] = f;
        wsi[FLAG_I + 1] = 1;
    }
}

// k0b: verify depth_values uniform over (h,w); clear flag on mismatch
__global__ void check_unif_kernel(const float* __restrict__ dvals, float* __restrict__ ws) {
    int idx = blockIdx.x * 256 + threadIdx.x;   // < B*D*HW
    int plane = idx / HWc;
    float v = dvals[idx];
    if (v != dvals[(size_t)plane * HWc]) ((int*)ws)[FLAG_I + 1] = 0;
}

// ---------- FAST PATH ----------
// kA: cross-correlation maps M[b,v,s,p] = valid * mean_c ref[c,p] * src[c, p+shift_s]
__global__ __launch_bounds__(256) void mapA_kernel(const float* __restrict__ feat,
                                                   float* __restrict__ ws) {
    const int* wsi = (const int*)ws;
    if (!(wsi[FLAG_I] & wsi[FLAG_I + 1])) return;
    int bv = blockIdx.y;                 // b*4 + (v-1)
    int ns = wsi[NS_I + bv];
    int s0 = blockIdx.z * 8;
    if (s0 >= ns) return;
    int b = bv >> 2, vm1 = (bv & 3) + 1;
    int p = blockIdx.x * 256 + threadIdx.x;
    int h = p / Wc, w = p % Wc;

    const float* refp = feat + (size_t)b * Cc * HWc + p;
    float rf[Cc];
    #pragma unroll
    for (int c = 0; c < Cc; ++c) rf[c] = refp[(size_t)c * HWc];

    const float* srcp = feat + (size_t)(vm1 * Bc + b) * Cc * HWc;
    int s1 = min(s0 + 8, ns);
    for (int s = s0; s < s1; ++s) {
        int dx = wsi[SHIFT_I + (bv * NSLOT + s) * 2];
        int dy = wsi[SHIFT_I + (bv * NSLOT + s) * 2 + 1];
        int sw = w + dx, sh = h + dy;
        bool valid = ((unsigned)sw < (unsigned)Wc) && ((unsigned)sh < (unsigned)Hc);
        int q = valid ? (sh * Wc + sw) : p;
        float dot = 0.f;
        #pragma unroll
        for (int c = 0; c < Cc; ++c) dot += rf[c] * srcp[(size_t)c * HWc + q];
        ws[WS_M + ((size_t)(bv * NSLOT + s)) * HWc + p] = valid ? dot * (1.f / 32.f) : 0.f;
    }
}

// kB: combine maps -> wvol, MLP -> view weight (max over d), similarity (d-major)
// wave layout: lane = dq*8 + pl; thread handles pixel p, depths dq*4..dq*4+3
__global__ __launch_bounds__(256) void combineB_kernel(
        const float* __restrict__ w0, const float* __restrict__ b0,
        const float* __restrict__ w1, const float* __restrict__ b1,
        const float* __restrict__ w2, const float* __restrict__ b2,
        float* __restrict__ ws, float* __restrict__ out) {
    const int* wsi = (const int*)ws;
    if (!(wsi[FLAG_I] & wsi[FLAG_I + 1])) return;
    __shared__ float mlpS[177];
    __shared__ float tap[4 * Dc * 9];     // this block's b: 4 views x 32 d x 9

    int tid = threadIdx.x;
    int lane = tid & 63;
    int dq = lane >> 3;
    int pl = lane & 7;
    int waveg = (blockIdx.x * 256 + tid) >> 6;
    int pg = waveg * 8 + pl;              // global pixel 0..B*HW-1
    int b = pg / HWc, p = pg % HWc;
    int bBlock = (blockIdx.x * 32) / HWc; // 32 consecutive pixels per block -> uniform b

    if (tid < 16) mlpS[tid] = w0[tid];
    else if (tid < 32) mlpS[tid] = b0[tid - 16];
    else if (tid < 160) mlpS[tid] = w1[tid - 32];
    else if (tid < 168) mlpS[tid] = b1[tid - 160];
    else if (tid < 176) mlpS[tid] = w2[tid - 168];
    else if (tid == 176) mlpS[176] = b2[0];
    #pragma unroll
    for (int k = 0; k < 5; ++k) {
        int i = tid + k * 256;
        if (i < 4 * Dc * 9) tap[i] = ws[WS_TAPID + bBlock * (4 * Dc * 9) + i];
    }
    __syncthreads();

    const float* Mb = ws + WS_M;
    float wvol[4][4];
    float vwp[4] = {0.f, 0.f, 0.f, 0.f};

    #pragma unroll
    for (int dl = 0; dl < 4; ++dl) {
        int d = dq * 4 + dl;
        float wv[4];
        #pragma unroll
        for (int v = 0; v < 4; ++v) {
            const float* rec = tap + (v * Dc + d) * 9;
            int i00 = __float_as_int(rec[0]);
            int i10 = __float_as_int(rec[1]);
            int i01 = __float_as_int(rec[2]);
            int i11 = __float_as_int(rec[3]);
            float wx = rec[4], wy = rec[5];
            size_t base = ((size_t)(b * 4 + v)) * NSLOT * HWc + p;
            float m00 = Mb[base + (size_t)i00 * HWc];
            float m10 = Mb[base + (size_t)i10 * HWc];
            float m01 = Mb[base + (size_t)i01 * HWc];
            float m11 = Mb[base + (size_t)i11 * HWc];
            float top = m00 + wx * (m10 - m00);
            float bot = m01 + wx * (m11 - m01);
            wv[v] = top + wy * (bot - top);
            wvol[dl][v] = wv[v];
        }
        // 4-wide MLP 1->16->8->1
        float h1[16][4];
        #pragma unroll
        for (int i = 0; i < 16; ++i) {
            float a = mlpS[i], bb = mlpS[16 + i];
            #pragma unroll
            for (int v = 0; v < 4; ++v) h1[i][v] = fmaxf(a * wv[v] + bb, 0.f);
        }
        float bias2 = mlpS[176];
        float y[4] = {bias2, bias2, bias2, bias2};
        const float4* w1v = (const float4*)(mlpS + 32);
        #pragma unroll
        for (int j = 0; j < 8; ++j) {
            float a0 = mlpS[160 + j];
            float acc[4] = {a0, a0, a0, a0};
            #pragma unroll
            for (int k = 0; k < 4; ++k) {
                float4 wq = w1v[j * 4 + k];
                #pragma unroll
                for (int v = 0; v < 4; ++v) {
                    acc[v] += wq.x * h1[4*k+0][v] + wq.y * h1[4*k+1][v]
                            + wq.z * h1[4*k+2][v] + wq.w * h1[4*k+3][v];
                }
            }
            float w2j = mlpS[168 + j];
            #pragma unroll
            for (int v = 0; v < 4; ++v) y[v] += w2j * fmaxf(acc[v], 0.f);
        }
        #pragma unroll
        for (int v = 0; v < 4; ++v) {
            float sig = __fdividef(1.f, 1.f + __expf(-y[v]));
            vwp[v] = fmaxf(vwp[v], sig);
        }
    }
    // reduce max over the 8 dq lanes
    #pragma unroll
    for (int v = 0; v < 4; ++v) {
        float m = vwp[v];
        m = fmaxf(m, __shfl_xor(m, 8));
        m = fmaxf(m, __shfl_xor(m, 16));
        m = fmaxf(m, __shfl_xor(m, 32));
        vwp[v] = m;
    }
    float invw = __fdividef(1.f, 1e-5f + vwp[0] + vwp[1] + vwp[2] + vwp[3]);
    #pragma unroll
    for (int dl = 0; dl < 4; ++dl) {
        float vol = wvol[dl][0] * vwp[0] + wvol[dl][1] * vwp[1]
                  + wvol[dl][2] * vwp[2] + wvol[dl][3] * vwp[3];
        ws[WS_SIM + ((size_t)(b * Dc + dq * 4 + dl)) * HWc + p] = vol * invw;
    }
    if (dq < 4)
        out[OUT_VW + ((size_t)(b * 4 + dq)) * HWc + p] = vwp[dq];
}

// ---------- FALLBACK PATH (generic; gated off when fast path valid) ----------
__global__ void transpose_kernel(const float* __restrict__ feat, float* __restrict__ ws) {
    const int* wsi = (const int*)ws;
    if (wsi[FLAG_I] & wsi[FLAG_I + 1]) return;
    __shared__ float tile[32][33];
    int slab = blockIdx.x;          // 0..9 (V*B)
    int pbase = blockIdx.y * 32;
    int tid = threadIdx.x;
    const float* src = feat + (size_t)slab * Cc * HWc;
    float* dst = ws + WS_FEATT + (size_t)slab * HWc * Cc;
    int cc = tid >> 5, pp = tid & 31;
    #pragma unroll
    for (int i = 0; i < 4; ++i) {
        int c = cc + 8 * i;
        tile[c][pp] = src[(size_t)c * HWc + pbase + pp];
    }
    __syncthreads();
    int c2 = tid & 31, p2 = tid >> 5;
    #pragma unroll
    for (int i = 0; i < 4; ++i) {
        int pq = p2 + 8 * i;
        dst[((size_t)(pbase + pq)) * 32 + c2] = tile[c2][pq];
    }
}

__global__ __launch_bounds__(256) void fb_main_kernel(
        const float* __restrict__ dvals,
        const float* __restrict__ w0, const float* __restrict__ b0,
        const float* __restrict__ w1, const float* __restrict__ b1,
        const float* __restrict__ w2, const float* __restrict__ b2,
        float* __restrict__ ws, float* __restrict__ out) {
    const int* wsi = (const int*)ws;
    if (wsi[FLAG_I] & wsi[FLAG_I + 1]) return;
    __shared__ float mlpS[177];
    __shared__ float rtS[48];

    int bid = blockIdx.x;
    int b = bid / (HWc / 8);
    int pblk = (bid % (HWc / 8)) * 8;
    int tid = threadIdx.x;
    int d = tid & 31;
    int pg = tid >> 5;
    int p = pblk + pg;
    int h = p / Wc, w = p % Wc;

    if (tid < 16) mlpS[tid] = w0[tid];
    else if (tid < 32) mlpS[tid] = b0[tid - 16];
    else if (tid < 160) mlpS[tid] = w1[tid - 32];
    else if (tid < 168) mlpS[tid] = b1[tid - 160];
    else if (tid < 176) mlpS[tid] = w2[tid - 168];
    else if (tid == 176) mlpS[176] = b2[0];
    if (tid >= 192 && tid < 240) rtS[tid - 192] = ws[WS_RT + b * 48 + (tid - 192)];
    __syncthreads();

    const float4* refp = (const float4*)(ws + WS_FEATT + ((size_t)b * HWc + p) * Cc);
    float4 rf[8];
    #pragma unroll
    for (int i = 0; i < 8; ++i) rf[i] = refp[i];

    float depth = dvals[((size_t)(b * Dc + d)) * HWc + p];
    float fx = (float)w, fy = (float)h;

    float sv[4];
    #pragma unroll
    for (int v = 0; v < 4; ++v) {
        const float* rt = rtS + v * 12;
        float px = (rt[0] * fx + rt[1] * fy + rt[2]) * depth + rt[9];
        float py = (rt[3] * fx + rt[4] * fy + rt[5]) * depth + rt[10];
        float pz = (rt[6] * fx + rt[7] * fy + rt[8]) * depth + rt[11];
        float xs = __fdividef(px, pz);
        float ys = __fdividef(py, pz);
        float fx0 = floorf(xs), fy0 = floorf(ys);
        float wx = xs - fx0, wy = ys - fy0;

        const float* featv = ws + WS_FEATT + ((size_t)((v + 1) * Bc + b)) * HWc * Cc;
        float acc = 0.f;
        #pragma unroll
        for (int ty = 0; ty < 2; ++ty) {
            #pragma unroll
            for (int tx = 0; tx < 2; ++tx) {
                float fxt = fx0 + (float)tx;
                float fyt = fy0 + (float)ty;
                bool valid = (fxt >= 0.f) && (fxt <= (float)(Wc - 1)) &&
                             (fyt >= 0.f) && (fyt <= (float)(Hc - 1));
                float wt = (tx ? wx : 1.f - wx) * (ty ? wy : 1.f - wy);
                if (valid) {
                    int ix = (int)fxt, iy = (int)fyt;
                    const float4* fp = (const float4*)(featv + ((size_t)iy * Wc + ix) * Cc);
                    float dot = 0.f;
                    #pragma unroll
                    for (int i = 0; i < 8; ++i) {
                        float4 fv = fp[i];
                        dot += fv.x * rf[i].x + fv.y * rf[i].y + fv.z * rf[i].z + fv.w * rf[i].w;
                    }
                    acc += wt * dot;
                }
            }
        }
        sv[v] = acc * (1.f / (float)Cc);
    }

    float h1[16][4];
    #pragma unroll
    for (int i = 0; i < 16; ++i) {
        float a = mlpS[i], bb = mlpS[16 + i];
        #pragma unroll
        for (int v = 0; v < 4; ++v) h1[i][v] = fmaxf(a * sv[v] + bb, 0.f);
    }
    float bias2 = mlpS[176];
    float y[4] = {bias2, bias2, bias2, bias2};
    const float4* w1v = (const float4*)(mlpS + 32);
    #pragma unroll
    for (int j = 0; j < 8; ++j) {
        float a0 = mlpS[160 + j];
        float acc[4] = {a0, a0, a0, a0};
        #pragma unroll
        for (int k = 0; k < 4; ++k) {
            float4 wq = w1v[j * 4 + k];
            #pragma unroll
            for (int v = 0; v < 4; ++v) {
                acc[v] += wq.x * h1[4*k+0][v] + wq.y * h1[4*k+1][v]
                        + wq.z * h1[4*k+2][v] + wq.w * h1[4*k+3][v];
            }
        }
        float w2j = mlpS[168 + j];
        #pragma unroll
        for (int v = 0; v < 4; ++v) y[v] += w2j * fmaxf(acc[v], 0.f);
    }

    float vw[4];
    #pragma unroll
    for (int v = 0; v < 4; ++v) {
        float m = __fdividef(1.f, 1.f + __expf(-y[v]));
        #pragma unroll
        for (int off = 16; off; off >>= 1) m = fmaxf(m, __shfl_xor(m, off));
        vw[v] = m;
    }

    float wsum = 1e-5f + vw[0] + vw[1] + vw[2] + vw[3];
    float vol = sv[0] * vw[0] + sv[1] * vw[1] + sv[2] * vw[2] + sv[3] * vw[3];
    ws[WS_SIM + ((size_t)(b * Dc + d)) * HWc + p] = __fdividef(vol, wsum);

    if (d < 4)
        out[OUT_VW + ((size_t)b * 4 + d) * HWc + p] = vw[d];
}

// ---------- SHARED TAIL ----------
// conv: collapsed 27-tap 3D conv on d-major sim; thread = pixel, 4 d-outputs (blockIdx.z quad)
__global__ __launch_bounds__(256) void conv_kernel(const float* __restrict__ regb,
                                                   float* __restrict__ ws) {
    int p = blockIdx.x * 256 + threadIdx.x;
    int b = blockIdx.y;
    int q = blockIdx.z;          // d-quad: outputs d = 4q..4q+3
    int h = p / Wc, w = p % Wc;

    float kw[27];
    #pragma unroll
    for (int i = 0; i < 27; ++i) kw[i] = ws[WS_KW + i];

    const float* simb = ws + WS_SIM + (size_t)b * Dc * HWc;
    float acc[4] = {0.f, 0.f, 0.f, 0.f};
    #pragma unroll
    for (int e = -1; e <= 4; ++e) {
        int dd = q * 4 + e;
        if (dd < 0 || dd >= Dc) continue;
        float val[3][3];
        #pragma unroll
        for (int i = 0; i < 3; ++i) {
            int hh = h + i - 1;
            #pragma unroll
            for (int j = 0; j < 3; ++j) {
                int wwp = w + j - 1;
                bool ok = ((unsigned)hh < (unsigned)Hc) && ((unsigned)wwp < (unsigned)Wc);
                val[i][j] = ok ? simb[(size_t)dd * HWc + hh * Wc + wwp] : 0.f;
            }
        }
        #pragma unroll
        for (int kd = 0; kd < 3; ++kd) {
            int tgt = e - kd + 1;             // output-slot in this quad
            if (tgt < 0 || tgt > 3) continue;
            float hs = 0.f;
            #pragma unroll
            for (int i = 0; i < 3; ++i)
                #pragma unroll
                for (int j = 0; j < 3; ++j)
                    hs += kw[kd * 9 + i * 3 + j] * val[i][j];
            acc[tgt] += hs;
        }
    }
    float bb = regb[0];
    #pragma unroll
    for (int r = 0; r < 4; ++r)
        ws[WS_PRE + ((size_t)(b * Dc + q * 4 + r)) * HWc + p] = acc[r] + bb;
}

// softmax over D (d-major pre); 4 threads per pixel
__global__ __launch_bounds__(256) void softmax_kernel(const float* __restrict__ dvals,
                                                      const float* __restrict__ ws,
                                                      float* __restrict__ out) {
    int idx = blockIdx.x * 256 + threadIdx.x;   // B*HW*4
    int lane = idx & 63;
    int t = lane >> 4;
    int pw = lane & 15;
    int P = (idx >> 6) * 16 + pw;
    int b = P / HWc, p = P % HWc;

    const float* preb = ws + WS_PRE + (size_t)b * Dc * HWc + p;
    float pr[8];
    #pragma unroll
    for (int k = 0; k < 8; ++k) pr[k] = preb[(size_t)(t * 8 + k) * HWc];

    float m = pr[0]; int am = t * 8;
    #pragma unroll
    for (int k = 1; k < 8; ++k) if (pr[k] > m) { m = pr[k]; am = t * 8 + k; }
    #pragma unroll
    for (int s = 16; s <= 32; s <<= 1) {
        float om = __shfl_xor(m, s);
        int oi = __shfl_xor(am, s);
        if (om > m || (om == m && oi < am)) { m = om; am = oi; }
    }
    float e[8]; float sum = 0.f;
    #pragma unroll
    for (int k = 0; k < 8; ++k) { e[k] = __expf(pr[k] - m); sum += e[k]; }
    #pragma unroll
    for (int s = 16; s <= 32; s <<= 1) sum += __shfl_xor(sum, s);
    float inv = __fdividef(1.f, sum);
    #pragma unroll
    for (int k = 0; k < 8; ++k)
        out[OUT_PROB + ((size_t)(b * Dc + t * 8 + k)) * HWc + p] = e[k] * inv;
    if (t == 0) {
        out[OUT_DEPTH + (size_t)b * HWc + p] = dvals[((size_t)(b * Dc + am)) * HWc + p];
        out[OUT_CONF + (size_t)b * HWc + p] = inv;
    }
}

extern "C" void kernel_launch(void* const* d_in, const int* in_sizes, int n_in,
                              void* d_out, int out_size, void* d_ws, size_t ws_size,
                              hipStream_t stream) {
    const float* features = (const float*)d_in[0];   // (V,B,C,H,W)
    const float* pm       = (const float*)d_in[1];   // (B,V,2,4,4)
    const float* dvals    = (const float*)d_in[2];   // (B,D,H,W)
    const float* pw_w0    = (const float*)d_in[3];
    const float* pw_b0    = (const float*)d_in[4];
    const float* pw_w1    = (const float*)d_in[5];
    const float* pw_b1    = (const float*)d_in[6];
    const float* pw_w2    = (const float*)d_in[7];
    const float* pw_b2    = (const float*)d_in[8];
    const float* reg_w    = (const float*)d_in[9];
    const float* reg_b    = (const float*)d_in[10];
    float* out = (float*)d_out;
    float* ws  = (float*)d_ws;

    prep_kernel<<<1, 64, 0, stream>>>(pm, reg_w, dvals, ws);
    check_unif_kernel<<<(Bc * Dc * HWc) / 256, 256, 0, stream>>>(dvals, ws);
    // fallback path (early-exits when fast path valid)
    transpose_kernel<<<dim3(Vc * Bc, HWc / 32), 256, 0, stream>>>(features, ws);
    // fast path
    mapA_kernel<<<dim3(HWc / 256, 8, 6), 256, 0, stream>>>(features, ws);
    fb_main_kernel<<<Bc * HWc / 8, 256, 0, stream>>>(dvals, pw_w0, pw_b0, pw_w1, pw_b1,
                                                     pw_w2, pw_b2, ws, out);
    combineB_kernel<<<(Bc * HWc * 8) / 256, 256, 0, stream>>>(pw_w0, pw_b0, pw_w1, pw_b1,
                                                              pw_w2, pw_b2, ws, out);
    // shared tail
    conv_kernel<<<dim3(HWc / 256, Bc, 8), 256, 0, stream>>>(reg_b, ws);
    softmax_kernel<<<(Bc * HWc * 4) / 256, 256, 0, stream>>>(dvals, ws, out);
}